// Round 12
// baseline (1727.331 us; speedup 1.0000x reference)
//
#include <hip/hip_runtime.h>
#include <stdint.h>

#define BDIM 4096
#define HDIM 2048
#define VDIM 32000
#define HALF (BDIM / 2)
#define IGNORE_INDEX (-100)

typedef int   v8i  __attribute__((ext_vector_type(8)));
typedef int   v4i  __attribute__((ext_vector_type(4)));
typedef float v16f __attribute__((ext_vector_type(16)));
typedef float f32x4 __attribute__((ext_vector_type(4)));
typedef __bf16 bf16x8 __attribute__((ext_vector_type(8)));

#define AS1 __attribute__((address_space(1)))
#define AS3 __attribute__((address_space(3)))

__device__ __forceinline__ unsigned short f2bf(float f) {
    union { float f; unsigned int u; } v; v.f = f;
    unsigned int u = v.u;
    unsigned int r = u + 0x7FFFu + ((u >> 16) & 1u);
    return (unsigned short)(r >> 16);
}

// fp32 -> fp8(e4m3, OCP). Loop-free, branch-free, wave-contiguous (round-9
// form, kept frozen: three cvt rewrites left "other" time ~336-364us, so the
// conversion pass is no longer the experiment — see round-10 post-mortem).
// x: scale 1. W: pre-scale by 64 (W ~ U(+-0.022) is subnormal in e4m3);
// the GEMM epilogue multiplies accumulators by 2^-6 (exact).

__device__ __forceinline__ void cvt4_store(const float4* __restrict__ s,
                                           unsigned* __restrict__ d,
                                           int j, float m) {
    float4 f0 = s[j];
    float4 f1 = s[j + 64];
    float4 f2 = s[j + 128];
    float4 f3 = s[j + 192];
    int w;
    w = __builtin_amdgcn_cvt_pk_fp8_f32(f0.x * m, f0.y * m, 0, false);
    w = __builtin_amdgcn_cvt_pk_fp8_f32(f0.z * m, f0.w * m, w, true);
    d[j] = (unsigned)w;
    w = __builtin_amdgcn_cvt_pk_fp8_f32(f1.x * m, f1.y * m, 0, false);
    w = __builtin_amdgcn_cvt_pk_fp8_f32(f1.z * m, f1.w * m, w, true);
    d[j + 64] = (unsigned)w;
    w = __builtin_amdgcn_cvt_pk_fp8_f32(f2.x * m, f2.y * m, 0, false);
    w = __builtin_amdgcn_cvt_pk_fp8_f32(f2.z * m, f2.w * m, w, true);
    d[j + 128] = (unsigned)w;
    w = __builtin_amdgcn_cvt_pk_fp8_f32(f3.x * m, f3.y * m, 0, false);
    w = __builtin_amdgcn_cvt_pk_fp8_f32(f3.z * m, f3.w * m, w, true);
    d[j + 192] = (unsigned)w;
}

// x: 4096*2048 = 2,097,152 float4 chunks = 2048 blocks * 1024.
__global__ __launch_bounds__(256) void cvt_x_kernel(const float* __restrict__ x,
                                                    uint8_t* __restrict__ xq) {
    const int t = blockIdx.x * 256 + threadIdx.x;
    const int j = ((t >> 6) << 8) + (t & 63);
    cvt4_store((const float4*)x, (unsigned*)xq, j, 1.0f);
}

// W: 32000*2048 = 16,384,000 chunks = 16000 blocks * 1024.
__global__ __launch_bounds__(256) void cvt_w_kernel(const float* __restrict__ W,
                                                    uint8_t* __restrict__ wq) {
    const int t = blockIdx.x * 256 + threadIdx.x;
    const int j = ((t >> 6) << 8) + (t & 63);
    cvt4_store((const float4*)W, (unsigned*)wq, j, 64.0f);
}

// Fused fp8 GEMM (x @ W^T) + per-row {sum exp, sum, target-logit}.
//
// ROUND-11: 256x128 tile (was 128x128). Mechanism: round-7/10 counters show
// the matrix pipe idle ~74% (MfmaUtil 26) with the full vmcnt(0)+lgkmcnt(0)
// drain at each __syncthreads exposed per K-step; round-8 proved manual
// barrier surgery causes a scratch-write pathology. The safe amortization is
// more MFMA per wave per barrier-pair: each of 4 waves owns a 128x64
// quadrant = acc[4][2] (16 MFMAs per BK=128 step, was 8). Also halves
// wq traffic and per-row atomics.
// __launch_bounds__(256,3): acc alone is 128 VGPR; a (256,4) 128-reg cap
// would force spills. LDS 48 KB -> 3 blocks/CU (LDS-limited anyway).
//
// LDS swizzle per 64-wide k-slice (unchanged, verified): 16-B chunk c of row
// r stored at position sigma_r(c) = (c + ((r>>1)&3)) & 3. Staging permutes
// the GLOBAL source chunk (all 4 chunks in one 64 B line) so global_load_lds
// keeps its contiguous lane*16 LDS mapping. Staging bases are multiples of
// 16 rows so (row>>1)&3 == (lane>>3)&3 holds for every 16-row group.
__global__ __launch_bounds__(256, 3)
void gemm_reduce_fp8(const uint8_t* __restrict__ A, const uint8_t* __restrict__ B,
                     const int* __restrict__ y,
                     float* __restrict__ sumexp, float* __restrict__ sumlog,
                     float* __restrict__ tlog) {
    __shared__ uint8_t sA[2][256 * 64];
    __shared__ uint8_t sB[2][128 * 64];

    const int tid = threadIdx.x;
    const int lane = tid & 63;
    const int wave = tid >> 6;
    const int wm = wave >> 1, wn = wave & 1;
    const int m0 = blockIdx.x * 256;
    const int v0 = blockIdx.y * 128;

    v16f acc[4][2];
#pragma unroll
    for (int i = 0; i < 4; i++)
#pragma unroll
        for (int j = 0; j < 2; j++)
#pragma unroll
            for (int r = 0; r < 16; r++) acc[i][j][r] = 0.f;

    // Staging: wave stages sA rows [wave*64, wave*64+64) (4 groups of 16)
    // and sB rows [wave*32, wave*32+32) (2 groups). Lane l -> row base+(l>>2),
    // chunk position p = l&3; source chunk c = (p - ((l>>3)&3)) & 3.
    const int srA = wave * 64 + (lane >> 2);
    const int srB = wave * 32 + (lane >> 2);
    const int sc  = ((lane & 3) - ((lane >> 3) & 3)) & 3;
    const uint8_t* gA0 = A + (size_t)(m0 + srA) * HDIM + sc * 16;
    const uint8_t* gB0 = B + (size_t)(v0 + srB) * HDIM + sc * 16;
    const int lofsA = (wave * 64) * 64;
    const int lofsB = (wave * 32) * 64;

    // Fragment reads (per lane): row l&31 of a 32-row tile, k-half h=l>>5
    // -> source chunks 2h, 2h+1 at swizzled positions.
    const int fr32 = lane & 31;
    const int h = lane >> 5;
    const int swr = (fr32 >> 1) & 3;
    const int pos0 = (2 * h + swr) & 3;
    const int pos1 = (2 * h + 1 + swr) & 3;
    int rA[4], rB[2];
#pragma unroll
    for (int mi = 0; mi < 4; mi++) rA[mi] = (wm * 128 + mi * 32 + fr32) * 64;
#pragma unroll
    for (int ni = 0; ni < 2; ni++) rB[ni] = (wn * 64 + ni * 32 + fr32) * 64;

    for (int kt = 0; kt < HDIM; kt += 128) {
        // Stage both 64-wide k-slices of the BK=128 step.
        // sA: 4 groups x 2 slices = 8 loads; sB: 2 x 2 = 4 loads per wave.
#pragma unroll
        for (int s = 0; s < 2; s++) {
#pragma unroll
            for (int p = 0; p < 4; p++)
                __builtin_amdgcn_global_load_lds(
                    (const AS1 unsigned int*)(gA0 + (size_t)(p * 16) * HDIM + kt + s * 64),
                    (AS3 unsigned int*)&sA[s][lofsA + p * 16 * 64], 16, 0, 0);
#pragma unroll
            for (int p = 0; p < 2; p++)
                __builtin_amdgcn_global_load_lds(
                    (const AS1 unsigned int*)(gB0 + (size_t)(p * 16) * HDIM + kt + s * 64),
                    (AS3 unsigned int*)&sB[s][lofsB + p * 16 * 64], 16, 0, 0);
        }
        __syncthreads();

#pragma unroll
        for (int s = 0; s < 2; s++) {
            v8i aF[4], bF[2];
#pragma unroll
            for (int mi = 0; mi < 4; mi++) {
                const v4i* pA = (const v4i*)&sA[s][rA[mi]];
                v4i a0 = pA[pos0], a1 = pA[pos1];
                aF[mi] = (v8i){a0[0], a0[1], a0[2], a0[3], a1[0], a1[1], a1[2], a1[3]};
            }
#pragma unroll
            for (int ni = 0; ni < 2; ni++) {
                const v4i* pB = (const v4i*)&sB[s][rB[ni]];
                v4i b0 = pB[pos0], b1 = pB[pos1];
                bF[ni] = (v8i){b0[0], b0[1], b0[2], b0[3], b1[0], b1[1], b1[2], b1[3]};
            }
#pragma unroll
            for (int mi = 0; mi < 4; mi++)
#pragma unroll
                for (int ni = 0; ni < 2; ni++)
                    acc[mi][ni] = __builtin_amdgcn_mfma_scale_f32_32x32x64_f8f6f4(
                        aF[mi], bF[ni], acc[mi][ni], 0, 0, 0,
                        0x7F7F7F7F, 0, 0x7F7F7F7F);
        }
        __syncthreads();
    }

    // Epilogue. 32x32 C/D layout: col = lane&31, row = (reg&3)+8*(reg>>2)+4*h.
    // Undo the W x64 pre-scale (exact).
    const float s64 = 0.015625f;
#pragma unroll
    for (int mi = 0; mi < 4; mi++) {
        const int baseRow = m0 + wm * 128 + mi * 32;
#pragma unroll
        for (int reg = 0; reg < 16; reg++) {
            float va = acc[mi][0][reg] * s64;
            float vb = acc[mi][1][reg] * s64;
            float e = __expf(va) + __expf(vb);
            float sm = va + vb;
#pragma unroll
            for (int off = 1; off < 32; off <<= 1) {
                e  += __shfl_xor(e, off);
                sm += __shfl_xor(sm, off);
            }
            int row = baseRow + (reg & 3) + 8 * (reg >> 2) + 4 * h;
            if (fr32 == 0) {
                atomicAdd(&sumexp[row], e);
                atomicAdd(&sumlog[row], sm);
            }
            int yv = y[row];
            int c0 = v0 + wn * 64 + fr32;
            if (c0 == yv) tlog[row] = va;
            if (c0 + 32 == yv) tlog[row] = vb;
        }
    }
}

// Fallback (small ws): fp32 inputs, in-kernel bf16 convert, 16x16x32 path.
__global__ __launch_bounds__(256, 4)
void gemm_reduce_f32(const float* __restrict__ A, const float* __restrict__ B,
                     const int* __restrict__ y,
                     float* __restrict__ sumexp, float* __restrict__ sumlog,
                     float* __restrict__ tlog) {
    __shared__ unsigned short sA[128 * 32];
    __shared__ unsigned short sB[128 * 32];

    const int tid  = threadIdx.x;
    const int lane = tid & 63;
    const int wave = tid >> 6;
    const int wm = wave >> 1, wn = wave & 1;
    const int m0 = blockIdx.x * 128;
    const int v0 = blockIdx.y * 128;
    const int fr = lane & 15;
    const int fq = lane >> 4;
    const int swz = (fr >> 1) & 3;

    f32x4 acc[4][4];
#pragma unroll
    for (int i = 0; i < 4; i++)
#pragma unroll
        for (int j = 0; j < 4; j++) acc[i][j] = (f32x4){0.f, 0.f, 0.f, 0.f};

    const int r8 = tid >> 3;
    const int kc = (tid & 7) * 4;
    for (int kt = 0; kt < HDIM; kt += 32) {
#pragma unroll
        for (int p = 0; p < 4; p++) {
            int row = p * 32 + r8;
            int pos = ((kc >> 3) ^ ((row >> 1) & 3)) * 8 + (kc & 7);
            float4 fa = *(const float4*)&A[(size_t)(m0 + row) * HDIM + kt + kc];
            float4 fb = *(const float4*)&B[(size_t)(v0 + row) * HDIM + kt + kc];
            ushort4 ua, ub;
            ua.x = f2bf(fa.x); ua.y = f2bf(fa.y); ua.z = f2bf(fa.z); ua.w = f2bf(fa.w);
            ub.x = f2bf(fb.x); ub.y = f2bf(fb.y); ub.z = f2bf(fb.z); ub.w = f2bf(fb.w);
            *(ushort4*)&sA[row * 32 + pos] = ua;
            *(ushort4*)&sB[row * 32 + pos] = ub;
        }
        __syncthreads();

        bf16x8 af[4], bf[4];
#pragma unroll
        for (int i = 0; i < 4; i++) {
            af[i] = *(const bf16x8*)&sA[(wm * 64 + i * 16 + fr) * 32 + (fq ^ swz) * 8];
            bf[i] = *(const bf16x8*)&sB[(wn * 64 + i * 16 + fr) * 32 + (fq ^ swz) * 8];
        }
#pragma unroll
        for (int mi = 0; mi < 4; mi++)
#pragma unroll
            for (int ni = 0; ni < 4; ni++)
                acc[mi][ni] = __builtin_amdgcn_mfma_f32_16x16x32_bf16(
                    af[mi], bf[ni], acc[mi][ni], 0, 0, 0);
        __syncthreads();
    }

    const int baseRow = m0 + wm * 64;
    const int cbase = v0 + wn * 64 + fr;
#pragma unroll
    for (int mi = 0; mi < 4; mi++) {
        float se[4] = {0.f, 0.f, 0.f, 0.f};
        float sl[4] = {0.f, 0.f, 0.f, 0.f};
#pragma unroll
        for (int ni = 0; ni < 4; ni++)
#pragma unroll
            for (int r = 0; r < 4; r++) {
                float v = acc[mi][ni][r];
                se[r] += __expf(v);
                sl[r] += v;
            }
#pragma unroll
        for (int r = 0; r < 4; r++) {
            float e = se[r], s = sl[r];
#pragma unroll
            for (int off = 1; off < 16; off <<= 1) {
                e += __shfl_xor(e, off);
                s += __shfl_xor(s, off);
            }
            int row = baseRow + mi * 16 + fq * 4 + r;
            if (fr == 0) {
                atomicAdd(&sumexp[row], e);
                atomicAdd(&sumlog[row], s);
            }
            int yv = y[row];
#pragma unroll
            for (int ni = 0; ni < 4; ni++)
                if (cbase + ni * 16 == yv) tlog[row] = acc[mi][ni][r];
        }
    }
}

// Final scalar loss from per-row stats. One block.
__global__ void finalize_kernel(const float* __restrict__ sumexp,
                                const float* __restrict__ sumlog,
                                const float* __restrict__ tlog,
                                const int* __restrict__ y,
                                float* __restrict__ out) {
    __shared__ float red[3][4];
    float s_nll = 0.f, s_or = 0.f, cnt = 0.f;
    for (int p = threadIdx.x; p < HALF; p += blockDim.x) {
        float lse_c = logf(sumexp[p]);
        float lse_r = logf(sumexp[p + HALF]);
        float mc = sumlog[p] * (1.0f / VDIM);
        float mr = sumlog[p + HALF] * (1.0f / VDIM);
        int yv = y[p];
        if (yv != IGNORE_INDEX) { s_nll += lse_c - tlog[p]; cnt += 1.f; }
        float ch = mc - lse_c, rj = mr - lse_r;
        float lo = (ch - rj) - (log1pf(-expf(ch)) - log1pf(-expf(rj)));
        float ls = fminf(lo, 0.f) - log1pf(expf(-fabsf(lo)));
        s_or += 0.1f * ls;
    }
    for (int off = 32; off; off >>= 1) {
        s_nll += __shfl_down(s_nll, off);
        s_or  += __shfl_down(s_or, off);
        cnt   += __shfl_down(cnt, off);
    }
    int wave = threadIdx.x >> 6, lane = threadIdx.x & 63;
    if (lane == 0) { red[0][wave] = s_nll; red[1][wave] = s_or; red[2][wave] = cnt; }
    __syncthreads();
    if (threadIdx.x == 0) {
        float tn = 0.f, to = 0.f, tc = 0.f;
        for (int w = 0; w < 4; w++) { tn += red[0][w]; to += red[1][w]; tc += red[2][w]; }
        out[0] = tn / fmaxf(tc, 1.f) - to / (float)HALF;
    }
}

extern "C" void kernel_launch(void* const* d_in, const int* in_sizes, int n_in,
                              void* d_out, int out_size, void* d_ws, size_t ws_size,
                              hipStream_t stream) {
    const float* x = (const float*)d_in[0];
    const float* W = (const float*)d_in[1];
    const int* y   = (const int*)d_in[2];
    float* out     = (float*)d_out;

    float* sumexp = (float*)d_ws;
    float* sumlog = sumexp + BDIM;
    float* tlog   = sumlog + BDIM;
    hipMemsetAsync(d_ws, 0, 3 * BDIM * sizeof(float), stream);

    const size_t bfoff = 65536;
    const size_t xcount = (size_t)BDIM * HDIM;
    const size_t wcount = (size_t)VDIM * HDIM;
    const size_t need = bfoff + xcount + wcount;   // fp8: 1 B/elem

    if (ws_size >= need) {
        uint8_t* xq = (uint8_t*)d_ws + bfoff;
        uint8_t* wq = xq + xcount;
        cvt_x_kernel<<<2048, 256, 0, stream>>>(x, xq);
        cvt_w_kernel<<<16000, 256, 0, stream>>>(W, wq);
        dim3 grid(BDIM / 256, VDIM / 128);
        gemm_reduce_fp8<<<grid, 256, 0, stream>>>(xq, wq, y, sumexp, sumlog, tlog);
    } else {
        dim3 grid(BDIM / 128, VDIM / 128);
        gemm_reduce_f32<<<grid, 256, 0, stream>>>(x, W, y, sumexp, sumlog, tlog);
    }
    finalize_kernel<<<1, 256, 0, stream>>>(sumexp, sumlog, tlog, y, out);
}

// Round 13
// 976.971 us; speedup vs baseline: 1.7680x; 1.7680x over previous
//
#include <hip/hip_runtime.h>
#include <stdint.h>

#define BDIM 4096
#define HDIM 2048
#define VDIM 32000
#define HALF (BDIM / 2)
#define IGNORE_INDEX (-100)

typedef int   v8i  __attribute__((ext_vector_type(8)));
typedef int   v4i  __attribute__((ext_vector_type(4)));
typedef float v16f __attribute__((ext_vector_type(16)));
typedef float f32x4 __attribute__((ext_vector_type(4)));
typedef __bf16 bf16x8 __attribute__((ext_vector_type(8)));

#define AS1 __attribute__((address_space(1)))
#define AS3 __attribute__((address_space(3)))

__device__ __forceinline__ unsigned short f2bf(float f) {
    union { float f; unsigned int u; } v; v.f = f;
    unsigned int u = v.u;
    unsigned int r = u + 0x7FFFu + ((u >> 16) & 1u);
    return (unsigned short)(r >> 16);
}

// fp32 -> fp8(e4m3, OCP). Loop-free, branch-free, wave-contiguous.
// x: scale 1. W: pre-scale by 64 (W ~ U(+-0.022) is subnormal in e4m3);
// the GEMM epilogue multiplies accumulators by 2^-6 (exact).
//
// ROUND-12 DIAGNOSTIC: cvt_w is launched TWICE (idempotent — same output
// bytes). Three cvt rewrites left "other" (total - gemm) invariant at
// ~336-364us while first-principles says cvt ~60-120us. The duplicate launch
// measures cvt_w directly: cvt_w_true = other_this_round - 336.

__device__ __forceinline__ void cvt4_store(const float4* __restrict__ s,
                                           unsigned* __restrict__ d,
                                           int j, float m) {
    float4 f0 = s[j];
    float4 f1 = s[j + 64];
    float4 f2 = s[j + 128];
    float4 f3 = s[j + 192];
    int w;
    w = __builtin_amdgcn_cvt_pk_fp8_f32(f0.x * m, f0.y * m, 0, false);
    w = __builtin_amdgcn_cvt_pk_fp8_f32(f0.z * m, f0.w * m, w, true);
    d[j] = (unsigned)w;
    w = __builtin_amdgcn_cvt_pk_fp8_f32(f1.x * m, f1.y * m, 0, false);
    w = __builtin_amdgcn_cvt_pk_fp8_f32(f1.z * m, f1.w * m, w, true);
    d[j + 64] = (unsigned)w;
    w = __builtin_amdgcn_cvt_pk_fp8_f32(f2.x * m, f2.y * m, 0, false);
    w = __builtin_amdgcn_cvt_pk_fp8_f32(f2.z * m, f2.w * m, w, true);
    d[j + 128] = (unsigned)w;
    w = __builtin_amdgcn_cvt_pk_fp8_f32(f3.x * m, f3.y * m, 0, false);
    w = __builtin_amdgcn_cvt_pk_fp8_f32(f3.z * m, f3.w * m, w, true);
    d[j + 192] = (unsigned)w;
}

// x: 4096*2048 = 2,097,152 float4 chunks = 2048 blocks * 1024.
__global__ __launch_bounds__(256) void cvt_x_kernel(const float* __restrict__ x,
                                                    uint8_t* __restrict__ xq) {
    const int t = blockIdx.x * 256 + threadIdx.x;
    const int j = ((t >> 6) << 8) + (t & 63);
    cvt4_store((const float4*)x, (unsigned*)xq, j, 1.0f);
}

// W: 32000*2048 = 16,384,000 chunks = 16000 blocks * 1024.
__global__ __launch_bounds__(256) void cvt_w_kernel(const float* __restrict__ W,
                                                    uint8_t* __restrict__ wq) {
    const int t = blockIdx.x * 256 + threadIdx.x;
    const int j = ((t >> 6) << 8) + (t & 63);
    cvt4_store((const float4*)W, (unsigned*)wq, j, 64.0f);
}

// Fused fp8 GEMM (x @ W^T) + per-row {sum exp, sum, target-logit}.
//
// LEDGER: r7/r10 baseline (this structure, stage->sync->compute) = 452us,
// MfmaUtil 26. r8 manual 2-phase (raw barrier + counted vmcnt + sched_barrier)
// = scratch pathology (WRITE 64->380MB), 536us. r11 256x128 tile (acc[4][2])
// = acc spill (VGPR 84, WRITE 2.5GB), 1403us. Both structural routes closed.
//
// ROUND-12: slice-level software pipeline using ONLY __syncthreads (no asm,
// no sched_barrier, no extra LDS, same acc[2][2]). Delta vs r7: the
// global_load_lds for slice i+1 is ISSUED before computing slice i, so the
// loads progress during the ~200+cyc compute phase instead of starting at
// the barrier. Buffers sA[0]/sA[1] alternate via 2x-unrolled loop with
// static indices (rule #20). Barrier count unchanged (1 per 64-slice).
// Tripwires: WRITE_SIZE must stay ~64MB, VGPR <= ~80, dur <= 452.
//
// LDS swizzle per 64-wide k-slice (verified): 16-B chunk c of row r stored
// at position sigma_r(c) = (c + ((r>>1)&3)) & 3. Staging permutes the GLOBAL
// source chunk (all 4 chunks lie in one 64 B line) so global_load_lds keeps
// its contiguous lane*16 LDS mapping.
__global__ __launch_bounds__(256, 4)
void gemm_reduce_fp8(const uint8_t* __restrict__ A, const uint8_t* __restrict__ B,
                     const int* __restrict__ y,
                     float* __restrict__ sumexp, float* __restrict__ sumlog,
                     float* __restrict__ tlog) {
    __shared__ uint8_t sA[2][128 * 64];
    __shared__ uint8_t sB[2][128 * 64];

    const int tid = threadIdx.x;
    const int lane = tid & 63;
    const int wave = tid >> 6;
    const int wm = wave >> 1, wn = wave & 1;
    const int m0 = blockIdx.x * 128;
    const int v0 = blockIdx.y * 128;

    v16f acc[2][2];
#pragma unroll
    for (int i = 0; i < 2; i++)
#pragma unroll
        for (int j = 0; j < 2; j++)
#pragma unroll
            for (int r = 0; r < 16; r++) acc[i][j][r] = 0.f;

    // Staging: wave stages rows [wave*32, wave*32+32) of sA and sB, 16 rows
    // per global_load_lds (64 lanes x 16 B). Lane l -> LDS row (l>>2), chunk
    // position p = l&3; source chunk c = (p - ((R>>1)&3)) & 3. With
    // R = wave*32 (+16) + (l>>2), (R>>1)&3 = (l>>3)&3 for both row halves.
    const int srow = wave * 32 + (lane >> 2);
    const int sc   = ((lane & 3) - ((lane >> 3) & 3)) & 3;
    const uint8_t* gA0 = A + (size_t)(m0 + srow) * HDIM + sc * 16;
    const uint8_t* gB0 = B + (size_t)(v0 + srow) * HDIM + sc * 16;
    const uint8_t* gA1 = gA0 + (size_t)16 * HDIM;
    const uint8_t* gB1 = gB0 + (size_t)16 * HDIM;
    const int lofs0 = (wave * 32) * 64;
    const int lofs1 = lofs0 + 16 * 64;

    // Fragment reads (per lane): row l&31 of the 32-row tile, k-half h=l>>5
    // -> source chunks 2h, 2h+1 at swizzled positions.
    const int fr32 = lane & 31;
    const int h = lane >> 5;
    const int swr = (fr32 >> 1) & 3;
    const int pos0 = (2 * h + swr) & 3;
    const int pos1 = (2 * h + 1 + swr) & 3;
    const int rA0 = (wm * 64 + fr32) * 64;
    const int rA1 = (wm * 64 + 32 + fr32) * 64;
    const int rB0 = (wn * 64 + fr32) * 64;
    const int rB1 = (wn * 64 + 32 + fr32) * 64;

    // One 64-wide k-slice = 4 global_load_lds per wave (1 KB each).
#define STAGE(BUF, SL) do {                                                     \
        __builtin_amdgcn_global_load_lds(                                       \
            (const AS1 unsigned int*)(gA0 + (size_t)(SL) * 64),                 \
            (AS3 unsigned int*)(&sA[BUF][lofs0]), 16, 0, 0);                    \
        __builtin_amdgcn_global_load_lds(                                       \
            (const AS1 unsigned int*)(gA1 + (size_t)(SL) * 64),                 \
            (AS3 unsigned int*)(&sA[BUF][lofs1]), 16, 0, 0);                    \
        __builtin_amdgcn_global_load_lds(                                       \
            (const AS1 unsigned int*)(gB0 + (size_t)(SL) * 64),                 \
            (AS3 unsigned int*)(&sB[BUF][lofs0]), 16, 0, 0);                    \
        __builtin_amdgcn_global_load_lds(                                       \
            (const AS1 unsigned int*)(gB1 + (size_t)(SL) * 64),                 \
            (AS3 unsigned int*)(&sB[BUF][lofs1]), 16, 0, 0);                    \
    } while (0)

#define COMPUTE(BUF) do {                                                       \
        const v4i* pA0 = (const v4i*)&sA[BUF][rA0];                             \
        const v4i* pA1 = (const v4i*)&sA[BUF][rA1];                             \
        const v4i* pB0 = (const v4i*)&sB[BUF][rB0];                             \
        const v4i* pB1 = (const v4i*)&sB[BUF][rB1];                             \
        v4i a00 = pA0[pos0], a01 = pA0[pos1];                                   \
        v4i a10 = pA1[pos0], a11 = pA1[pos1];                                   \
        v4i b00 = pB0[pos0], b01 = pB0[pos1];                                   \
        v4i b10 = pB1[pos0], b11 = pB1[pos1];                                   \
        v8i af0 = {a00[0], a00[1], a00[2], a00[3], a01[0], a01[1], a01[2], a01[3]}; \
        v8i af1 = {a10[0], a10[1], a10[2], a10[3], a11[0], a11[1], a11[2], a11[3]}; \
        v8i bf0 = {b00[0], b00[1], b00[2], b00[3], b01[0], b01[1], b01[2], b01[3]}; \
        v8i bf1 = {b10[0], b10[1], b10[2], b10[3], b11[0], b11[1], b11[2], b11[3]}; \
        acc[0][0] = __builtin_amdgcn_mfma_scale_f32_32x32x64_f8f6f4(            \
            af0, bf0, acc[0][0], 0, 0, 0, 0x7F7F7F7F, 0, 0x7F7F7F7F);           \
        acc[0][1] = __builtin_amdgcn_mfma_scale_f32_32x32x64_f8f6f4(            \
            af0, bf1, acc[0][1], 0, 0, 0, 0x7F7F7F7F, 0, 0x7F7F7F7F);           \
        acc[1][0] = __builtin_amdgcn_mfma_scale_f32_32x32x64_f8f6f4(            \
            af1, bf0, acc[1][0], 0, 0, 0, 0x7F7F7F7F, 0, 0x7F7F7F7F);           \
        acc[1][1] = __builtin_amdgcn_mfma_scale_f32_32x32x64_f8f6f4(            \
            af1, bf1, acc[1][1], 0, 0, 0, 0x7F7F7F7F, 0, 0x7F7F7F7F);           \
    } while (0)

    // 32 k-slices of 64. Pipeline: stage slice i+1, compute slice i, barrier.
    // Races: STAGE(1,*) writes buf1 while COMPUTE(0) reads buf0 (disjoint);
    // the __syncthreads after both (a) drains the just-issued loads (vmcnt0)
    // and (b) orders all waves' reads of buf0 before the next STAGE(0,*)
    // overwrite. Plain __syncthreads semantics only.
    STAGE(0, 0);
    __syncthreads();
    for (int i = 0; i < 30; i += 2) {
        STAGE(1, i + 1);
        COMPUTE(0);
        __syncthreads();
        STAGE(0, i + 2);
        COMPUTE(1);
        __syncthreads();
    }
    STAGE(1, 31);
    COMPUTE(0);
    __syncthreads();
    COMPUTE(1);

#undef STAGE
#undef COMPUTE

    // Epilogue. 32x32 C/D layout: col = lane&31, row = (reg&3)+8*(reg>>2)+4*h.
    // Undo the W x64 pre-scale (exact).
    const float s64 = 0.015625f;
#pragma unroll
    for (int mi = 0; mi < 2; mi++) {
        const int baseRow = m0 + wm * 64 + mi * 32;
#pragma unroll
        for (int reg = 0; reg < 16; reg++) {
            float va = acc[mi][0][reg] * s64;
            float vb = acc[mi][1][reg] * s64;
            float e = __expf(va) + __expf(vb);
            float sm = va + vb;
#pragma unroll
            for (int off = 1; off < 32; off <<= 1) {
                e  += __shfl_xor(e, off);
                sm += __shfl_xor(sm, off);
            }
            int row = baseRow + (reg & 3) + 8 * (reg >> 2) + 4 * h;
            if (fr32 == 0) {
                atomicAdd(&sumexp[row], e);
                atomicAdd(&sumlog[row], sm);
            }
            int yv = y[row];
            int c0 = v0 + wn * 64 + fr32;
            if (c0 == yv) tlog[row] = va;
            if (c0 + 32 == yv) tlog[row] = vb;
        }
    }
}

// Fallback (small ws): fp32 inputs, in-kernel bf16 convert, 16x16x32 path.
__global__ __launch_bounds__(256, 4)
void gemm_reduce_f32(const float* __restrict__ A, const float* __restrict__ B,
                     const int* __restrict__ y,
                     float* __restrict__ sumexp, float* __restrict__ sumlog,
                     float* __restrict__ tlog) {
    __shared__ unsigned short sA[128 * 32];
    __shared__ unsigned short sB[128 * 32];

    const int tid  = threadIdx.x;
    const int lane = tid & 63;
    const int wave = tid >> 6;
    const int wm = wave >> 1, wn = wave & 1;
    const int m0 = blockIdx.x * 128;
    const int v0 = blockIdx.y * 128;
    const int fr = lane & 15;
    const int fq = lane >> 4;
    const int swz = (fr >> 1) & 3;

    f32x4 acc[4][4];
#pragma unroll
    for (int i = 0; i < 4; i++)
#pragma unroll
        for (int j = 0; j < 4; j++) acc[i][j] = (f32x4){0.f, 0.f, 0.f, 0.f};

    const int r8 = tid >> 3;
    const int kc = (tid & 7) * 4;
    for (int kt = 0; kt < HDIM; kt += 32) {
#pragma unroll
        for (int p = 0; p < 4; p++) {
            int row = p * 32 + r8;
            int pos = ((kc >> 3) ^ ((row >> 1) & 3)) * 8 + (kc & 7);
            float4 fa = *(const float4*)&A[(size_t)(m0 + row) * HDIM + kt + kc];
            float4 fb = *(const float4*)&B[(size_t)(v0 + row) * HDIM + kt + kc];
            ushort4 ua, ub;
            ua.x = f2bf(fa.x); ua.y = f2bf(fa.y); ua.z = f2bf(fa.z); ua.w = f2bf(fa.w);
            ub.x = f2bf(fb.x); ub.y = f2bf(fb.y); ub.z = f2bf(fb.z); ub.w = f2bf(fb.w);
            *(ushort4*)&sA[row * 32 + pos] = ua;
            *(ushort4*)&sB[row * 32 + pos] = ub;
        }
        __syncthreads();

        bf16x8 af[4], bf[4];
#pragma unroll
        for (int i = 0; i < 4; i++) {
            af[i] = *(const bf16x8*)&sA[(wm * 64 + i * 16 + fr) * 32 + (fq ^ swz) * 8];
            bf[i] = *(const bf16x8*)&sB[(wn * 64 + i * 16 + fr) * 32 + (fq ^ swz) * 8];
        }
#pragma unroll
        for (int mi = 0; mi < 4; mi++)
#pragma unroll
            for (int ni = 0; ni < 4; ni++)
                acc[mi][ni] = __builtin_amdgcn_mfma_f32_16x16x32_bf16(
                    af[mi], bf[ni], acc[mi][ni], 0, 0, 0);
        __syncthreads();
    }

    const int baseRow = m0 + wm * 64;
    const int cbase = v0 + wn * 64 + fr;
#pragma unroll
    for (int mi = 0; mi < 4; mi++) {
        float se[4] = {0.f, 0.f, 0.f, 0.f};
        float sl[4] = {0.f, 0.f, 0.f, 0.f};
#pragma unroll
        for (int ni = 0; ni < 4; ni++)
#pragma unroll
            for (int r = 0; r < 4; r++) {
                float v = acc[mi][ni][r];
                se[r] += __expf(v);
                sl[r] += v;
            }
#pragma unroll
        for (int r = 0; r < 4; r++) {
            float e = se[r], s = sl[r];
#pragma unroll
            for (int off = 1; off < 16; off <<= 1) {
                e += __shfl_xor(e, off);
                s += __shfl_xor(s, off);
            }
            int row = baseRow + mi * 16 + fq * 4 + r;
            if (fr == 0) {
                atomicAdd(&sumexp[row], e);
                atomicAdd(&sumlog[row], s);
            }
            int yv = y[row];
#pragma unroll
            for (int ni = 0; ni < 4; ni++)
                if (cbase + ni * 16 == yv) tlog[row] = acc[mi][ni][r];
        }
    }
}

// Final scalar loss from per-row stats. One block.
__global__ void finalize_kernel(const float* __restrict__ sumexp,
                                const float* __restrict__ sumlog,
                                const float* __restrict__ tlog,
                                const int* __restrict__ y,
                                float* __restrict__ out) {
    __shared__ float red[3][4];
    float s_nll = 0.f, s_or = 0.f, cnt = 0.f;
    for (int p = threadIdx.x; p < HALF; p += blockDim.x) {
        float lse_c = logf(sumexp[p]);
        float lse_r = logf(sumexp[p + HALF]);
        float mc = sumlog[p] * (1.0f / VDIM);
        float mr = sumlog[p + HALF] * (1.0f / VDIM);
        int yv = y[p];
        if (yv != IGNORE_INDEX) { s_nll += lse_c - tlog[p]; cnt += 1.f; }
        float ch = mc - lse_c, rj = mr - lse_r;
        float lo = (ch - rj) - (log1pf(-expf(ch)) - log1pf(-expf(rj)));
        float ls = fminf(lo, 0.f) - log1pf(expf(-fabsf(lo)));
        s_or += 0.1f * ls;
    }
    for (int off = 32; off; off >>= 1) {
        s_nll += __shfl_down(s_nll, off);
        s_or  += __shfl_down(s_or, off);
        cnt   += __shfl_down(cnt, off);
    }
    int wave = threadIdx.x >> 6, lane = threadIdx.x & 63;
    if (lane == 0) { red[0][wave] = s_nll; red[1][wave] = s_or; red[2][wave] = cnt; }
    __syncthreads();
    if (threadIdx.x == 0) {
        float tn = 0.f, to = 0.f, tc = 0.f;
        for (int w = 0; w < 4; w++) { tn += red[0][w]; to += red[1][w]; tc += red[2][w]; }
        out[0] = tn / fmaxf(tc, 1.f) - to / (float)HALF;
    }
}

extern "C" void kernel_launch(void* const* d_in, const int* in_sizes, int n_in,
                              void* d_out, int out_size, void* d_ws, size_t ws_size,
                              hipStream_t stream) {
    const float* x = (const float*)d_in[0];
    const float* W = (const float*)d_in[1];
    const int* y   = (const int*)d_in[2];
    float* out     = (float*)d_out;

    float* sumexp = (float*)d_ws;
    float* sumlog = sumexp + BDIM;
    float* tlog   = sumlog + BDIM;
    hipMemsetAsync(d_ws, 0, 3 * BDIM * sizeof(float), stream);

    const size_t bfoff = 65536;
    const size_t xcount = (size_t)BDIM * HDIM;
    const size_t wcount = (size_t)VDIM * HDIM;
    const size_t need = bfoff + xcount + wcount;   // fp8: 1 B/elem

    if (ws_size >= need) {
        uint8_t* xq = (uint8_t*)d_ws + bfoff;
        uint8_t* wq = xq + xcount;
        cvt_x_kernel<<<2048, 256, 0, stream>>>(x, xq);
        // DIAGNOSTIC (round 12): cvt_w launched twice (idempotent) to measure
        // its true duration: cvt_w ~= (total - gemm) - 336us baseline "other".
        // Remove the duplicate once measured.
        cvt_w_kernel<<<16000, 256, 0, stream>>>(W, wq);
        cvt_w_kernel<<<16000, 256, 0, stream>>>(W, wq);
        dim3 grid(BDIM / 128, VDIM / 128);
        gemm_reduce_fp8<<<grid, 256, 0, stream>>>(xq, wq, y, sumexp, sumlog, tlog);
    } else {
        dim3 grid(BDIM / 128, VDIM / 128);
        gemm_reduce_f32<<<grid, 256, 0, stream>>>(x, W, y, sumexp, sumlog, tlog);
    }
    finalize_kernel<<<1, 256, 0, stream>>>(sumexp, sumlog, tlog, y, out);
}